// Round 1
// 2181.607 us; speedup vs baseline: 2.0404x; 2.0404x over previous
//
#include <hip/hip_runtime.h>

// ---------------------------------------------------------------------------
// BlockLSTM forward, MI355X (gfx950).  T=512, B=64, I=U=512.
// out = [h_seq (T,B,U) | final_cs (B,U) | final_h (B,U)] fp32
//
// z-columns permuted unit-major: col' = u*4 + g  (orig col = g*512 + u).
// zxp stored in MFMA 32x32 C-fragment order: [t][cb][rt][lane][reg] bf16.
// hbf stored in MFMA 32x32 A-fragment order:
//   elem offset(t, row, unit) = t*32768 + (row>>5)*16384 + (unit>>3)*256
//                               + (row&31)*8 + (unit&7)
//
// SYNC (this version): NO epochs, NO producer fence. All hbf slots 1..512 are
// pre-poisoned with bf16 NaN (0x7FC0) at init. h = tanh*sigmoid is never NaN,
// so consumers poll the DATA itself: speculatively load fragments, retry while
// any dword reinterprets as NaN (NaN-propagating float-sum check, dword
// granular so store tearing is harmless). This removes the epoch round-trip
// and the producer's s_waitcnt vmcnt(0) from the critical path.
//
// Recurrence: 64 blocks x 128 thr (2 waves). Wave wv of block cb owns K-half
// [wv*256, +256) of the h_prev GEMM for cols [cb*32,+32); partials combined
// via a double-buffered LDS exchange (one barrier/step). Gates: thread =
// (row = tid&63, units cb*8 + wv*4 .. +4), sigmoid/tanh via v_rcp_f32.
//
// ws layout (~164.1 MB):
//   [0,   4MB)        wT   bf16 [2048 permuted cols][1024 k]
//   [4MB, 132MB)      zxp  bf16 [512][64][2][64][16]
//   [132MB, +32.06MB) hbf  bf16 [513 slots][32768]  (slot t = h_{t-1})
// ---------------------------------------------------------------------------

#define T_STEPS 512
#define NB 64
#define NU 512
#define NI 512
#define KTOT 1024
#define ZCOLS 2048
#define HSEQ_ELEMS (T_STEPS * NB * NU)
#define POISON64 0x7FC07FC07FC07FC0ull

typedef float    floatx4   __attribute__((ext_vector_type(4)));
typedef float    floatx16  __attribute__((ext_vector_type(16)));
typedef __bf16   bf16x8    __attribute__((ext_vector_type(8)));
typedef unsigned short ushortx8 __attribute__((ext_vector_type(8)));
typedef unsigned long long ull_t;

static __device__ __forceinline__ unsigned short f2bf(float f) {
  unsigned int u = __builtin_bit_cast(unsigned int, f);
  u += 0x7fffu + ((u >> 16) & 1u);  // RNE
  return (unsigned short)(u >> 16);
}
static __device__ __forceinline__ float bf2f(unsigned short h) {
  unsigned int u = ((unsigned int)h) << 16;
  return __builtin_bit_cast(float, u);
}
static __device__ __forceinline__ float sigmoidf_(float x) {
  return __builtin_amdgcn_rcpf(1.0f + __expf(-x));
}
// stable fast tanh: t = exp(-2|x|); r = sign(x) * (1-t)/(1+t)  (rcp approx)
static __device__ __forceinline__ float fast_tanhf(float x) {
  const float ax = fabsf(x);
  const float t = __expf(-2.0f * ax);
  const float r = (1.0f - t) * __builtin_amdgcn_rcpf(1.0f + t);
  return copysignf(r, x);
}
static __device__ __forceinline__ bf16x8 ldfrag(const unsigned short* p) {
  ushortx8 v = *reinterpret_cast<const ushortx8*>(p);
  return __builtin_bit_cast(bf16x8, v);
}
static __device__ __forceinline__ ull_t pack4bf(float a, float b, float c, float d) {
  return (ull_t)f2bf(a) | ((ull_t)f2bf(b) << 16) | ((ull_t)f2bf(c) << 32) |
         ((ull_t)f2bf(d) << 48);
}
// 16B fragment load bypassing L1/L2 (agent-coherent read from IF$).
static __device__ __forceinline__ bf16x8 ld_agent16(const unsigned short* p) {
  ull_t lo = __hip_atomic_load((const ull_t*)p, __ATOMIC_RELAXED, __HIP_MEMORY_SCOPE_AGENT);
  ull_t hi = __hip_atomic_load((const ull_t*)(p + 4), __ATOMIC_RELAXED, __HIP_MEMORY_SCOPE_AGENT);
  struct P { ull_t a, b; } s{lo, hi};
  return __builtin_bit_cast(bf16x8, s);
}

// ---------------------------------------------------------------------------
// init: poison hbf slots 1..512 with bf16-NaN; slot0 = bf16(h0) in A-frag
// order. Normal stores: kernel-end release flushes L2, rec kernel reads via
// agent loads (L2-bypassed) -> coherent. grid 2056 x 256.
// ---------------------------------------------------------------------------
__global__ __launch_bounds__(256) void init_kernel(const float* __restrict__ h0,
                                                   unsigned short* __restrict__ hbf) {
  const int j = blockIdx.x * 256 + threadIdx.x;  // 0..526335
  if (j < 524288) {
    // 64B of poison per thread over slots 1..512 (512*64KB total)
    ull_t* p = reinterpret_cast<ull_t*>(&hbf[32768 + (size_t)j * 32]);
#pragma unroll
    for (int r = 0; r < 8; ++r) p[r] = POISON64;
  } else {
    const int k = j - 524288;  // 0..2047, two (row,chunk) pairs each
#pragma unroll
    for (int p2 = 0; p2 < 2; ++p2) {
      const int i = k * 2 + p2;  // 0..4095
      const int row = i >> 6, chunk = i & 63;
      const float* src = &h0[row * NU + chunk * 8];
      const ull_t lo = pack4bf(src[0], src[1], src[2], src[3]);
      const ull_t hi = pack4bf(src[4], src[5], src[6], src[7]);
      const size_t off = ((size_t)((row >> 5) * 64 + chunk) * 32 + (row & 31)) * 8;
      *reinterpret_cast<ull_t*>(&hbf[off]) = lo;
      *reinterpret_cast<ull_t*>(&hbf[off + 4]) = hi;
    }
  }
}

// ---------------------------------------------------------------------------
// transpose + permute: wT[(u*4+g)][k] = bf16(w[k][g*512+u])
// ---------------------------------------------------------------------------
__global__ __launch_bounds__(256) void transpose_w_kernel(
    const float* __restrict__ w, unsigned short* __restrict__ wT) {
  __shared__ float tile[32][33];
  const int u0 = blockIdx.x * 32;
  const int k0 = blockIdx.y * 32;
  const int g = blockIdx.z;
  const int tx = threadIdx.x & 31, ty = threadIdx.x >> 5;
#pragma unroll
  for (int r = 0; r < 4; ++r) {
    const int k = ty + r * 8;
    tile[k][tx] = w[(size_t)(k0 + k) * ZCOLS + g * 512 + u0 + tx];
  }
  __syncthreads();
#pragma unroll
  for (int r = 0; r < 4; ++r) {
    const int u = ty + r * 8;
    wT[(size_t)((u0 + u) * 4 + g) * KTOT + k0 + tx] = f2bf(tile[tx][u]);
  }
}

// ---------------------------------------------------------------------------
// gemm: zxp = (x @ wx + b) in permuted cols, stored in 32x32 C-fragment order.
// ---------------------------------------------------------------------------
__global__ __launch_bounds__(256) void gemm_zx_kernel(
    const float* __restrict__ x, const unsigned short* __restrict__ wT,
    const float* __restrict__ bias, unsigned short* __restrict__ zxp) {
  __shared__ __align__(16) unsigned short As[128][32];
  __shared__ __align__(16) unsigned short Bs[128][32];
  const int m0 = blockIdx.y * 128;
  const int n0 = blockIdx.x * 128;
  const int tid = threadIdx.x;
  const int wid = tid >> 6, lane = tid & 63;
  const int quad = lane >> 4, nl = lane & 15;
  const int wm = (wid & 1) * 64, wn = (wid >> 1) * 64;
  const int srow = tid >> 3;
  const int skk = (tid & 7) * 4;

  floatx4 acc[4][4] = {};

  for (int kt = 0; kt < 16; ++kt) {
    const int k0 = kt * 32;
    __syncthreads();
#pragma unroll
    for (int r = 0; r < 4; ++r) {
      const int row = r * 32 + srow;
      const float4 v =
          *reinterpret_cast<const float4*>(&x[(size_t)(m0 + row) * NI + k0 + skk]);
      *reinterpret_cast<ull_t*>(&As[row][skk]) = pack4bf(v.x, v.y, v.z, v.w);
      *reinterpret_cast<ull_t*>(&Bs[row][skk]) =
          *reinterpret_cast<const ull_t*>(&wT[(size_t)(n0 + row) * KTOT + k0 + skk]);
    }
    __syncthreads();
    bf16x8 af[4], bfr[4];
#pragma unroll
    for (int i = 0; i < 4; ++i) {
      af[i] = ldfrag(&As[wm + i * 16 + nl][quad * 8]);
      bfr[i] = ldfrag(&Bs[wn + i * 16 + nl][quad * 8]);
    }
#pragma unroll
    for (int i = 0; i < 4; ++i)
#pragma unroll
      for (int j = 0; j < 4; ++j)
        acc[i][j] =
            __builtin_amdgcn_mfma_f32_16x16x32_bf16(af[i], bfr[j], acc[i][j], 0, 0, 0);
  }

  float bv[4];
#pragma unroll
  for (int j = 0; j < 4; ++j) {
    const int colp = n0 + wn + j * 16 + nl;
    bv[j] = bias[(colp & 3) * 512 + (colp >> 2)];
  }
#pragma unroll
  for (int i = 0; i < 4; ++i) {
    const int browb = wm + i * 16 + quad * 4;
    const int t = (m0 + browb) >> 6;
    const int rt = (browb >> 5) & 1;
    const int hi = (browb & 31) >> 3;
    const int qb = (browb >> 2) & 1;
#pragma unroll
    for (int j = 0; j < 4; ++j) {
      const int colp = n0 + wn + j * 16 + nl;
      const int cbl = colp >> 5;
      const int lanep = (colp & 31) + 32 * qb;
      const ull_t packed =
          pack4bf(acc[i][j][0] + bv[j], acc[i][j][1] + bv[j],
                  acc[i][j][2] + bv[j], acc[i][j][3] + bv[j]);
      *reinterpret_cast<ull_t*>(
          &zxp[((((size_t)t * 64 + cbl) * 2 + rt) * 64 + lanep) * 16 + hi * 4]) = packed;
    }
  }
}

// ---------------------------------------------------------------------------
// recurrence: 64 blocks x 128 thr (2 waves). Wave wv owns K-half wv*256..+256.
// Poison-validated speculative loads; one __syncthreads per step; double-
// buffered LDS z-exchange.
// ---------------------------------------------------------------------------
__global__ __launch_bounds__(128, 1) void lstm_rec_kernel(
    const unsigned short* __restrict__ zxp, const unsigned short* __restrict__ wT,
    const float* __restrict__ cs_init, float* __restrict__ out,
    unsigned short* __restrict__ hbf) {
  const int tid = threadIdx.x;
  const int lane = tid & 63;
  const int wv = tid >> 6;               // 0/1: K-half
  const int cb = blockIdx.x;             // units [cb*8, +8)
  const int rl = lane & 31, q = lane >> 5;
  const int u0 = cb * 8;

  // resident B fragments: this wave's K-half of wh rows, cols [cb*32,+32)
  bf16x8 Bf[16];
#pragma unroll
  for (int i = 0; i < 16; ++i)
    Bf[i] = ldfrag(&wT[(size_t)(cb * 32 + rl) * KTOT + 512 + (wv * 16 + i) * 16 + q * 8]);

  // gate mapping: thread = (row = lane, units u0 + wv*4 .. +4)
  float csv[4];
#pragma unroll
  for (int j = 0; j < 4; ++j) csv[j] = cs_init[lane * NU + u0 + wv * 4 + j];

  __shared__ float zsh[2][2][64][33];  // [t&1][wave][row][col]

  for (int t = 0; t < T_STEPS; ++t) {
    // zx prefetch (wave0 only; wave1's acc starts at 0)
    uint4 z00 = {}, z01 = {}, z10 = {}, z11 = {};
    if (wv == 0) {
      const uint4* zp0 = reinterpret_cast<const uint4*>(
          &zxp[((((size_t)t * 64 + cb) * 2 + 0) * 64 + lane) * 16]);
      const uint4* zp1 = reinterpret_cast<const uint4*>(
          &zxp[((((size_t)t * 64 + cb) * 2 + 1) * 64 + lane) * 16]);
      z00 = zp0[0]; z01 = zp0[1]; z10 = zp1[0]; z11 = zp1[1];
    }

    // speculative K-half fragment loads + poison validation (retry whole set).
    // Any still-poison dword reinterprets as f32 NaN -> sum turns NaN.
    const unsigned short* hp = hbf + (size_t)t * (NB * NU) + lane * 8;
    bf16x8 A0[2][8], A1[2][8];
    {
      int guard = 0;
      while (true) {
#pragma unroll
        for (int c2 = 0; c2 < 2; ++c2)
#pragma unroll
          for (int kk = 0; kk < 8; ++kk) {
            A0[c2][kk] = ld_agent16(hp + (wv * 2 + c2) * 4096 + kk * 512);
            A1[c2][kk] = ld_agent16(hp + 16384 + (wv * 2 + c2) * 4096 + kk * 512);
          }
        floatx4 va = {0.0f, 0.0f, 0.0f, 0.0f};
        floatx4 vb = {0.0f, 0.0f, 0.0f, 0.0f};
#pragma unroll
        for (int c2 = 0; c2 < 2; ++c2)
#pragma unroll
          for (int kk = 0; kk < 8; ++kk) {
            va += __builtin_bit_cast(floatx4, A0[c2][kk]);
            vb += __builtin_bit_cast(floatx4, A1[c2][kk]);
          }
        const float c = ((va.x + va.y) + (va.z + va.w)) +
                        ((vb.x + vb.y) + (vb.z + vb.w));
        if (!__any(c != c) || ++guard >= (1 << 18)) break;
      }
    }

    // acc init: wave0 = zx (+bias), wave1 = 0
    floatx16 acc0 = {}, acc1 = {};
    if (wv == 0) {
      const unsigned* pa = reinterpret_cast<const unsigned*>(&z00);
      const unsigned* pb = reinterpret_cast<const unsigned*>(&z01);
      const unsigned* pc = reinterpret_cast<const unsigned*>(&z10);
      const unsigned* pd = reinterpret_cast<const unsigned*>(&z11);
#pragma unroll
      for (int i = 0; i < 4; ++i) {
        acc0[2 * i] = bf2f((unsigned short)(pa[i] & 0xffffu));
        acc0[2 * i + 1] = bf2f((unsigned short)(pa[i] >> 16));
        acc0[8 + 2 * i] = bf2f((unsigned short)(pb[i] & 0xffffu));
        acc0[8 + 2 * i + 1] = bf2f((unsigned short)(pb[i] >> 16));
        acc1[2 * i] = bf2f((unsigned short)(pc[i] & 0xffffu));
        acc1[2 * i + 1] = bf2f((unsigned short)(pc[i] >> 16));
        acc1[8 + 2 * i] = bf2f((unsigned short)(pd[i] & 0xffffu));
        acc1[8 + 2 * i + 1] = bf2f((unsigned short)(pd[i] >> 16));
      }
    }

    // MFMA: all fragments already valid in regs -> uninterrupted chain
#pragma unroll
    for (int c2 = 0; c2 < 2; ++c2)
#pragma unroll
      for (int kk = 0; kk < 8; ++kk) {
        acc0 = __builtin_amdgcn_mfma_f32_32x32x16_bf16(A0[c2][kk], Bf[c2 * 8 + kk],
                                                       acc0, 0, 0, 0);
        acc1 = __builtin_amdgcn_mfma_f32_32x32x16_bf16(A1[c2][kk], Bf[c2 * 8 + kk],
                                                       acc1, 0, 0, 0);
      }

    // partial z -> LDS (double-buffered by t&1)
    const int pb_ = t & 1;
#pragma unroll
    for (int reg = 0; reg < 16; ++reg) {
      const int rowc = (reg & 3) + 4 * q + 8 * (reg >> 2);
      zsh[pb_][wv][rowc][rl] = acc0[reg];
      zsh[pb_][wv][32 + rowc][rl] = acc1[reg];
    }
    __syncthreads();

    // gates: thread -> (row = lane, 4 units); z cols (u*4..+3) = (i, ci, f, o)
    float hout[4];
#pragma unroll
    for (int j = 0; j < 4; ++j) {
      const int c = (wv * 4 + j) * 4;
      const float4 a = *reinterpret_cast<const float4*>(&zsh[pb_][0][lane][c]);
      const float4 b = *reinterpret_cast<const float4*>(&zsh[pb_][1][lane][c]);
      const float zi = a.x + b.x, zci = a.y + b.y, zf = a.z + b.z, zo = a.w + b.w;
      const float iv = sigmoidf_(zi);
      const float civ = fast_tanhf(zci);
      const float fv = sigmoidf_(zf + 1.0f);  // forget_bias
      const float ov = sigmoidf_(zo);
      csv[j] = civ * iv + csv[j] * fv;
      hout[j] = fast_tanhf(csv[j]) * ov;
    }

    // h broadcast: ONE 8B agent store per thread, no fence, no flag.
    unsigned short* hw = &hbf[(size_t)(t + 1) * (NB * NU) + (size_t)(lane >> 5) * 16384 +
                              cb * 256 + (lane & 31) * 8 + wv * 4];
    __hip_atomic_store(reinterpret_cast<ull_t*>(hw),
                       pack4bf(hout[0], hout[1], hout[2], hout[3]),
                       __ATOMIC_RELAXED, __HIP_MEMORY_SCOPE_AGENT);

    // out stores (off the critical path)
    float* op = &out[((size_t)t * NB + lane) * NU + u0 + wv * 4];
    *reinterpret_cast<float4*>(op) = make_float4(hout[0], hout[1], hout[2], hout[3]);
    if (t == T_STEPS - 1) {
      float* cp = &out[HSEQ_ELEMS + lane * NU + u0 + wv * 4];
      *reinterpret_cast<float4*>(cp) = make_float4(csv[0], csv[1], csv[2], csv[3]);
      float* hp2 = &out[HSEQ_ELEMS + NB * NU + lane * NU + u0 + wv * 4];
      *reinterpret_cast<float4*>(hp2) = make_float4(hout[0], hout[1], hout[2], hout[3]);
    }
  }
}

// ---------------------------------------------------------------------------
extern "C" void kernel_launch(void* const* d_in, const int* in_sizes, int n_in,
                              void* d_out, int out_size, void* d_ws, size_t ws_size,
                              hipStream_t stream) {
  const float* x = (const float*)d_in[0];
  const float* cs0 = (const float*)d_in[1];
  const float* h0 = (const float*)d_in[2];
  const float* w = (const float*)d_in[3];
  const float* bias = (const float*)d_in[4];
  float* out = (float*)d_out;

  char* ws = (char*)d_ws;
  unsigned short* wT = (unsigned short*)(ws);
  unsigned short* zxp = (unsigned short*)(ws + (size_t)(4 << 20));
  unsigned short* hbf = (unsigned short*)(ws + (size_t)(132 << 20));

  init_kernel<<<dim3(2056), 256, 0, stream>>>(h0, hbf);
  transpose_w_kernel<<<dim3(16, 32, 4), 256, 0, stream>>>(w, wT);
  gemm_zx_kernel<<<dim3(16, 256), 256, 0, stream>>>(x, wT, bias, zxp);
  lstm_rec_kernel<<<dim3(64), 128, 0, stream>>>(zxp, wT, cs0, out, hbf);
}

// Round 2
// 1308.459 us; speedup vs baseline: 3.4020x; 1.6673x over previous
//
#include <hip/hip_runtime.h>

// ---------------------------------------------------------------------------
// BlockLSTM forward, MI355X (gfx950).  T=512, B=64, I=U=512.
// out = [h_seq (T,B,U) | final_cs (B,U) | final_h (B,U)] fp32
//
// z-columns permuted unit-major: col' = u*4 + g  (orig col = g*512 + u).
// zxp stored in MFMA 32x32 C-fragment order: [t][cb][rt][lanep][16] bf16.
// hbf stored in A-fragment order:
//   elem offset(t, row, unit) = t*32768 + (row>>5)*16384 + (unit>>3)*256
//                               + (row&31)*8 + (unit&7)
//
// SYNC: data-is-flag. hbf slots 1..512 pre-poisoned with bf16 NaN (0x7FC0);
// h = tanh*sigmoid is never NaN. Consumers speculatively load fragments and
// retry while any consumed DWORD reinterprets as f32 NaN (each dword comes
// from a single 4B producer store, so tearing is impossible at dword grain).
//
// Recurrence (this version): batch rows are INDEPENDENT, so split by rows,
// not K: 256 blocks x 64 thr (1 wave). Block (cb,qr) owns units [cb*8,+8)
// x rows [qr*16,+16). Full K=512 per wave with 16x16x32 MFMAs (16 A-frags,
// 32 B-frags resident, 4 independent chains of 8). NO barrier, NO cross-wave
// exchange. Poll loads for step t+1 are pre-issued right after the h-store
// of step t (out-store acks overlap the poll RTT). Gates: 2 units/lane.
//
// ws layout (~164.1 MB):
//   [0,   4MB)        wT   bf16 [2048 permuted cols][1024 k]
//   [4MB, 132MB)      zxp  bf16 [512][64][2][64][16]
//   [132MB, +32.06MB) hbf  bf16 [513 slots][32768]  (slot t = h_{t-1})
// ---------------------------------------------------------------------------

#define T_STEPS 512
#define NB 64
#define NU 512
#define NI 512
#define KTOT 1024
#define ZCOLS 2048
#define HSEQ_ELEMS (T_STEPS * NB * NU)
#define POISON64 0x7FC07FC07FC07FC0ull

typedef float    floatx4   __attribute__((ext_vector_type(4)));
typedef __bf16   bf16x8    __attribute__((ext_vector_type(8)));
typedef unsigned short ushortx8 __attribute__((ext_vector_type(8)));
typedef unsigned long long ull_t;

static __device__ __forceinline__ unsigned short f2bf(float f) {
  unsigned int u = __builtin_bit_cast(unsigned int, f);
  u += 0x7fffu + ((u >> 16) & 1u);  // RNE
  return (unsigned short)(u >> 16);
}
static __device__ __forceinline__ float bf2f(unsigned short h) {
  unsigned int u = ((unsigned int)h) << 16;
  return __builtin_bit_cast(float, u);
}
static __device__ __forceinline__ float asf(unsigned int u) {
  return __builtin_bit_cast(float, u);
}
static __device__ __forceinline__ float sigmoidf_(float x) {
  return __builtin_amdgcn_rcpf(1.0f + __expf(-x));
}
// stable fast tanh: t = exp(-2|x|); r = sign(x) * (1-t)/(1+t)  (rcp approx)
static __device__ __forceinline__ float fast_tanhf(float x) {
  const float ax = fabsf(x);
  const float t = __expf(-2.0f * ax);
  const float r = (1.0f - t) * __builtin_amdgcn_rcpf(1.0f + t);
  return copysignf(r, x);
}
static __device__ __forceinline__ bf16x8 ldfrag(const unsigned short* p) {
  ushortx8 v = *reinterpret_cast<const ushortx8*>(p);
  return __builtin_bit_cast(bf16x8, v);
}
static __device__ __forceinline__ ull_t pack4bf(float a, float b, float c, float d) {
  return (ull_t)f2bf(a) | ((ull_t)f2bf(b) << 16) | ((ull_t)f2bf(c) << 32) |
         ((ull_t)f2bf(d) << 48);
}
static __device__ __forceinline__ bf16x8 mkfrag(ull_t lo, ull_t hi) {
  struct P { ull_t a, b; } s{lo, hi};
  return __builtin_bit_cast(bf16x8, s);
}

// ---------------------------------------------------------------------------
// init: poison hbf slots 1..512 with bf16-NaN; slot0 = bf16(h0) in A-frag
// order. grid 2056 x 256.
// ---------------------------------------------------------------------------
__global__ __launch_bounds__(256) void init_kernel(const float* __restrict__ h0,
                                                   unsigned short* __restrict__ hbf) {
  const int j = blockIdx.x * 256 + threadIdx.x;  // 0..526335
  if (j < 524288) {
    ull_t* p = reinterpret_cast<ull_t*>(&hbf[32768 + (size_t)j * 32]);
#pragma unroll
    for (int r = 0; r < 8; ++r) p[r] = POISON64;
  } else {
    const int k = j - 524288;  // 0..2047
#pragma unroll
    for (int p2 = 0; p2 < 2; ++p2) {
      const int i = k * 2 + p2;  // 0..4095
      const int row = i >> 6, chunk = i & 63;
      const float* src = &h0[row * NU + chunk * 8];
      const ull_t lo = pack4bf(src[0], src[1], src[2], src[3]);
      const ull_t hi = pack4bf(src[4], src[5], src[6], src[7]);
      const size_t off = ((size_t)((row >> 5) * 64 + chunk) * 32 + (row & 31)) * 8;
      *reinterpret_cast<ull_t*>(&hbf[off]) = lo;
      *reinterpret_cast<ull_t*>(&hbf[off + 4]) = hi;
    }
  }
}

// ---------------------------------------------------------------------------
// transpose + permute: wT[(u*4+g)][k] = bf16(w[k][g*512+u])
// ---------------------------------------------------------------------------
__global__ __launch_bounds__(256) void transpose_w_kernel(
    const float* __restrict__ w, unsigned short* __restrict__ wT) {
  __shared__ float tile[32][33];
  const int u0 = blockIdx.x * 32;
  const int k0 = blockIdx.y * 32;
  const int g = blockIdx.z;
  const int tx = threadIdx.x & 31, ty = threadIdx.x >> 5;
#pragma unroll
  for (int r = 0; r < 4; ++r) {
    const int k = ty + r * 8;
    tile[k][tx] = w[(size_t)(k0 + k) * ZCOLS + g * 512 + u0 + tx];
  }
  __syncthreads();
#pragma unroll
  for (int r = 0; r < 4; ++r) {
    const int u = ty + r * 8;
    wT[(size_t)((u0 + u) * 4 + g) * KTOT + k0 + tx] = f2bf(tile[tx][u]);
  }
}

// ---------------------------------------------------------------------------
// gemm: zxp = (x @ wx + b) in permuted cols, stored in 32x32 C-fragment order.
// ---------------------------------------------------------------------------
__global__ __launch_bounds__(256) void gemm_zx_kernel(
    const float* __restrict__ x, const unsigned short* __restrict__ wT,
    const float* __restrict__ bias, unsigned short* __restrict__ zxp) {
  __shared__ __align__(16) unsigned short As[128][32];
  __shared__ __align__(16) unsigned short Bs[128][32];
  const int m0 = blockIdx.y * 128;
  const int n0 = blockIdx.x * 128;
  const int tid = threadIdx.x;
  const int wid = tid >> 6, lane = tid & 63;
  const int quad = lane >> 4, nl = lane & 15;
  const int wm = (wid & 1) * 64, wn = (wid >> 1) * 64;
  const int srow = tid >> 3;
  const int skk = (tid & 7) * 4;

  floatx4 acc[4][4] = {};

  for (int kt = 0; kt < 16; ++kt) {
    const int k0 = kt * 32;
    __syncthreads();
#pragma unroll
    for (int r = 0; r < 4; ++r) {
      const int row = r * 32 + srow;
      const float4 v =
          *reinterpret_cast<const float4*>(&x[(size_t)(m0 + row) * NI + k0 + skk]);
      *reinterpret_cast<ull_t*>(&As[row][skk]) = pack4bf(v.x, v.y, v.z, v.w);
      *reinterpret_cast<ull_t*>(&Bs[row][skk]) =
          *reinterpret_cast<const ull_t*>(&wT[(size_t)(n0 + row) * KTOT + k0 + skk]);
    }
    __syncthreads();
    bf16x8 af[4], bfr[4];
#pragma unroll
    for (int i = 0; i < 4; ++i) {
      af[i] = ldfrag(&As[wm + i * 16 + nl][quad * 8]);
      bfr[i] = ldfrag(&Bs[wn + i * 16 + nl][quad * 8]);
    }
#pragma unroll
    for (int i = 0; i < 4; ++i)
#pragma unroll
      for (int j = 0; j < 4; ++j)
        acc[i][j] =
            __builtin_amdgcn_mfma_f32_16x16x32_bf16(af[i], bfr[j], acc[i][j], 0, 0, 0);
  }

  float bv[4];
#pragma unroll
  for (int j = 0; j < 4; ++j) {
    const int colp = n0 + wn + j * 16 + nl;
    bv[j] = bias[(colp & 3) * 512 + (colp >> 2)];
  }
#pragma unroll
  for (int i = 0; i < 4; ++i) {
    const int browb = wm + i * 16 + quad * 4;
    const int t = (m0 + browb) >> 6;
    const int rt = (browb >> 5) & 1;
    const int hi = (browb & 31) >> 3;
    const int qb = (browb >> 2) & 1;
#pragma unroll
    for (int j = 0; j < 4; ++j) {
      const int colp = n0 + wn + j * 16 + nl;
      const int cbl = colp >> 5;
      const int lanep = (colp & 31) + 32 * qb;
      const ull_t packed =
          pack4bf(acc[i][j][0] + bv[j], acc[i][j][1] + bv[j],
                  acc[i][j][2] + bv[j], acc[i][j][3] + bv[j]);
      *reinterpret_cast<ull_t*>(
          &zxp[((((size_t)t * 64 + cbl) * 2 + rt) * 64 + lanep) * 16 + hi * 4]) = packed;
    }
  }
}

// ---------------------------------------------------------------------------
// recurrence: 256 blocks x 64 thr (1 wave). Block (cb = bid>>2, qr = bid&3):
// units [cb*8,+8), rows [qr*16,+16). Fully independent waves, no barriers.
// ---------------------------------------------------------------------------
__global__ __launch_bounds__(64, 1) void lstm_rec_kernel(
    const unsigned short* __restrict__ zxp, const unsigned short* __restrict__ wT,
    const float* __restrict__ cs_init, float* __restrict__ out,
    unsigned short* __restrict__ hbf) {
  const int lane = threadIdx.x;
  const int bid = blockIdx.x;
  const int cb = bid >> 2;               // units [cb*8, +8), z-cols [cb*32,+32)
  const int qr = bid & 3;                // rows [qr*16, +16)
  const int l15 = lane & 15, lq = lane >> 4;  // lq = 0..3
  const int u0 = cb * 8;
  const int rowg = qr * 16 + l15;        // this lane's batch row (gates/output)
  const int rh = qr >> 1;                // row-half bit (hbf / zxp rt)
  const int r31 = (qr & 1) * 16 + l15;   // row & 31

  // B fragments resident: 2 colfrags x 16 kfrags (wh rows k=512.., cols cb*32+..)
  bf16x8 Bf[2][16];
#pragma unroll
  for (int cf = 0; cf < 2; ++cf)
#pragma unroll
    for (int kf = 0; kf < 16; ++kf)
      Bf[cf][kf] = ldfrag(
          &wT[(size_t)(cb * 32 + cf * 16 + l15) * KTOT + 512 + kf * 32 + lq * 8]);

  // cell state: lane = (row rowg, units u0 + 2*lq, +1)
  float csv[2];
  csv[0] = cs_init[rowg * NU + u0 + 2 * lq];
  csv[1] = cs_init[rowg * NU + u0 + 2 * lq + 1];

  __shared__ float zsh[2][16][33];

  // A-fragment load state (16 frags x 16B as lo/hi 8B pairs)
  ull_t AL[16], AH[16];
  const unsigned short* hpbase =
      hbf + (size_t)rh * 16384 + (size_t)r31 * 8;  // + t*32768 + (kf*4+lq)*256

  auto issueA = [&](int t) {
    const unsigned short* hp = hpbase + (size_t)t * 32768 + lq * 256;
#pragma unroll
    for (int kf = 0; kf < 16; ++kf) {
      const unsigned short* p = hp + kf * 1024;
      AL[kf] = __hip_atomic_load((const ull_t*)p, __ATOMIC_RELAXED,
                                 __HIP_MEMORY_SCOPE_AGENT);
      AH[kf] = __hip_atomic_load((const ull_t*)(p + 4), __ATOMIC_RELAXED,
                                 __HIP_MEMORY_SCOPE_AGENT);
    }
  };

  // zx: per colfrag one 8B (4 bf16 = acc regs 0..3 for this lane's rows)
  const int hi4 = (qr & 1) * 2 + (lq >> 1);
  const int lanep_base = l15 + 32 * (lq & 1);
  ull_t zx0, zx1;
  auto issueZ = [&](int t) {
    const size_t base = ((((size_t)t * 64 + cb) * 2 + rh) * 64);
    zx0 = *reinterpret_cast<const ull_t*>(
        &zxp[(base + lanep_base) * 16 + 4 * hi4]);
    zx1 = *reinterpret_cast<const ull_t*>(
        &zxp[(base + lanep_base + 16) * 16 + 4 * hi4]);
  };

  issueA(0);
  issueZ(0);

  for (int t = 0; t < T_STEPS; ++t) {
    // ---- validate pre-issued A loads; retry until no poison dword ----
    {
      int guard = 0;
      while (true) {
        float sx = 0.f, sy = 0.f, sz = 0.f, sw = 0.f;
#pragma unroll
        for (int kf = 0; kf < 16; ++kf) {
          sx += asf((unsigned)(AL[kf] & 0xffffffffu));
          sy += asf((unsigned)(AL[kf] >> 32));
          sz += asf((unsigned)(AH[kf] & 0xffffffffu));
          sw += asf((unsigned)(AH[kf] >> 32));
        }
        const float c = (sx + sy) + (sz + sw);
        if (!__any(c != c) || ++guard >= (1 << 18)) break;
        issueA(t);
      }
    }

    // ---- acc init: chain0 <- zx, chain1 <- 0;  4 chains of 8 MFMAs ----
    floatx4 a00, a01;
#pragma unroll
    for (int r = 0; r < 4; ++r) {
      a00[r] = bf2f((unsigned short)((zx0 >> (16 * r)) & 0xffffu));
      a01[r] = bf2f((unsigned short)((zx1 >> (16 * r)) & 0xffffu));
    }
    floatx4 a10 = {0.f, 0.f, 0.f, 0.f}, a11 = {0.f, 0.f, 0.f, 0.f};
#pragma unroll
    for (int kf = 0; kf < 8; ++kf) {
      const bf16x8 Alo = mkfrag(AL[kf], AH[kf]);
      const bf16x8 Ahi = mkfrag(AL[8 + kf], AH[8 + kf]);
      a00 = __builtin_amdgcn_mfma_f32_16x16x32_bf16(Alo, Bf[0][kf], a00, 0, 0, 0);
      a01 = __builtin_amdgcn_mfma_f32_16x16x32_bf16(Alo, Bf[1][kf], a01, 0, 0, 0);
      a10 = __builtin_amdgcn_mfma_f32_16x16x32_bf16(Ahi, Bf[0][8 + kf], a10, 0, 0, 0);
      a11 = __builtin_amdgcn_mfma_f32_16x16x32_bf16(Ahi, Bf[1][8 + kf], a11, 0, 0, 0);
    }
    const floatx4 zc0 = a00 + a10;  // cols cf=0 (cb*32 + 0..15)
    const floatx4 zc1 = a01 + a11;  // cols cf=1 (cb*32 + 16..31)

    // ---- in-wave transpose via LDS (no barrier; wave-ordered DS) ----
    const int pb = t & 1;
#pragma unroll
    for (int r = 0; r < 4; ++r) {
      zsh[pb][lq * 4 + r][l15] = zc0[r];
      zsh[pb][lq * 4 + r][16 + l15] = zc1[r];
    }
    const float4 g0 = *reinterpret_cast<const float4*>(&zsh[pb][l15][8 * lq]);
    const float4 g1 = *reinterpret_cast<const float4*>(&zsh[pb][l15][8 * lq + 4]);

    // ---- gates: 2 units/lane; cols (u*4..+3) = (i, ci, f, o) ----
    float hout[2];
    {
      const float iv = sigmoidf_(g0.x);
      const float civ = fast_tanhf(g0.y);
      const float fv = sigmoidf_(g0.z + 1.0f);  // forget_bias
      const float ov = sigmoidf_(g0.w);
      csv[0] = civ * iv + csv[0] * fv;
      hout[0] = fast_tanhf(csv[0]) * ov;
    }
    {
      const float iv = sigmoidf_(g1.x);
      const float civ = fast_tanhf(g1.y);
      const float fv = sigmoidf_(g1.z + 1.0f);
      const float ov = sigmoidf_(g1.w);
      csv[1] = civ * iv + csv[1] * fv;
      hout[1] = fast_tanhf(csv[1]) * ov;
    }

    // ---- h broadcast: one 4B agent store (critical); then pre-issue next ----
    unsigned short* hw = &hbf[(size_t)(t + 1) * 32768 + (size_t)rh * 16384 +
                              cb * 256 + r31 * 8 + 2 * lq];
    const unsigned hv = (unsigned)f2bf(hout[0]) | ((unsigned)f2bf(hout[1]) << 16);
    __hip_atomic_store(reinterpret_cast<unsigned*>(hw), hv, __ATOMIC_RELAXED,
                       __HIP_MEMORY_SCOPE_AGENT);
    asm volatile("" ::: "memory");  // keep store before the speculative loads
    if (t + 1 < T_STEPS) {
      issueA(t + 1);  // speculative iteration-0 of next step's poll
      issueZ(t + 1);
    }

    // ---- out stores (acks overlap next poll's RTT) ----
    float* op = &out[((size_t)t * NB + rowg) * NU + u0 + 2 * lq];
    op[0] = hout[0];
    op[1] = hout[1];
    if (t == T_STEPS - 1) {
      float* cp = &out[HSEQ_ELEMS + (size_t)rowg * NU + u0 + 2 * lq];
      cp[0] = csv[0];
      cp[1] = csv[1];
      float* hp2 = &out[HSEQ_ELEMS + NB * NU + (size_t)rowg * NU + u0 + 2 * lq];
      hp2[0] = hout[0];
      hp2[1] = hout[1];
    }
  }
}

// ---------------------------------------------------------------------------
extern "C" void kernel_launch(void* const* d_in, const int* in_sizes, int n_in,
                              void* d_out, int out_size, void* d_ws, size_t ws_size,
                              hipStream_t stream) {
  const float* x = (const float*)d_in[0];
  const float* cs0 = (const float*)d_in[1];
  const float* h0 = (const float*)d_in[2];
  const float* w = (const float*)d_in[3];
  const float* bias = (const float*)d_in[4];
  float* out = (float*)d_out;

  char* ws = (char*)d_ws;
  unsigned short* wT = (unsigned short*)(ws);
  unsigned short* zxp = (unsigned short*)(ws + (size_t)(4 << 20));
  unsigned short* hbf = (unsigned short*)(ws + (size_t)(132 << 20));

  init_kernel<<<dim3(2056), 256, 0, stream>>>(h0, hbf);
  transpose_w_kernel<<<dim3(16, 32, 4), 256, 0, stream>>>(w, wT);
  gemm_zx_kernel<<<dim3(16, 256), 256, 0, stream>>>(x, wT, bias, zxp);
  lstm_rec_kernel<<<dim3(256), 64, 0, stream>>>(zxp, wT, cs0, out, hbf);
}